// Round 1
// baseline (308.390 us; speedup 1.0000x reference)
//
#include <hip/hip_runtime.h>
#include <stdint.h>

typedef int   int32x4  __attribute__((ext_vector_type(4)));
typedef float floatx4  __attribute__((ext_vector_type(4)));

#define B_ROWS 131072
#define DK 512           // K (= D)
#define FN 512           // N (= F)
#define BM 128           // rows per block
#define NPANEL 128       // cols per panel
#define A_SCALE_F ((float)(127.0 / 6.0))

// ---------------- prepass: quantize weights into B-fragment-friendly layout ----
// grid 4 x 128 threads; thread handles one output column n.
// wq layout: [FN][DK] int8, k-contiguous  -> MFMA B fragment = 16B straight load.
__global__ void wq_quant_kernel(const float* __restrict__ kern,  // [DK][FN]
                                int8_t* __restrict__ wq,         // [FN][DK]
                                float* __restrict__ cs) {        // [FN]
  const int n = blockIdx.x * 128 + threadIdx.x;
  float wmax = 0.f;
  for (int d = 0; d < DK; ++d) {
    wmax = fmaxf(wmax, fabsf(kern[d * FN + n]));
  }
  const float wb = fmaxf(wmax, 1e-6f);
  const float wscale = 127.f / wb;          // f32 divide, matches jnp
  cs[n] = A_SCALE_F * wscale;               // f32 mul, matches jnp a_scale*w_scale
  uint32_t* wq32 = (uint32_t*)(wq + (size_t)n * DK);
  for (int d4 = 0; d4 < DK / 4; ++d4) {
    uint32_t p = 0;
#pragma unroll
    for (int j = 0; j < 4; ++j) {
      float v = kern[(d4 * 4 + j) * FN + n] * wscale;
      v = floorf(v + 0.5f);                 // AQT round: floor(v+0.5)
      v = fminf(fmaxf(v, -127.f), 127.f);
      p |= ((uint32_t)((int)v & 255)) << (8 * j);   // byte j = k (little-endian)
    }
    wq32[d4] = p;
  }
}

// ---------------- main GEMM ----------------------------------------------------
// 1024 blocks x 256 threads (4 waves as 2x2 over the 128x128 panel).
// LDS: x quantized to int8, XOR-swizzled to avoid stride-512B bank conflicts.
__global__ __launch_bounds__(256, 2)
void aqt_gemm_kernel(const float* __restrict__ x,     // [B_ROWS][DK]
                     const int8_t* __restrict__ wq,   // [FN][DK]
                     const float* __restrict__ cs,    // [FN]
                     const float* __restrict__ bias,  // [FN]
                     float* __restrict__ out) {       // [B_ROWS][FN]
  __shared__ __align__(16) char xq[BM * DK];          // 64 KB

  const int tid  = threadIdx.x;
  const int lane = tid & 63;
  const int wv   = tid >> 6;        // 0..3
  const int wr   = wv >> 1;         // wave row (0..1) -> 64 rows each
  const int wc   = wv & 1;          // wave col (0..1) -> 64 cols each
  const int lr   = lane & 15;       // fragment row/col
  const int lg   = lane >> 4;       // k-group (0..3)

  const size_t mBase = (size_t)blockIdx.x * BM;
  const float* xg = x + mBase * DK;

  // ---- stage: quantize x tile (fp32 -> int8) into swizzled LDS ----
  {
    const int c4 = tid & 127;       // float4 index within a row (16B granules)
    const int r0 = tid >> 7;        // 0..1
    for (int r = r0; r < BM; r += 2) {
      floatx4 v = *(const floatx4*)(xg + (size_t)r * DK + c4 * 4);
      uint32_t p = 0;
#pragma unroll
      for (int j = 0; j < 4; ++j) {
        float q = floorf(v[j] * A_SCALE_F + 0.5f);   // AQT round
        q = fminf(fmaxf(q, -127.f), 127.f);
        p |= ((uint32_t)((int)q & 255)) << (8 * j);
      }
      const int byteoff = (c4 * 4) ^ ((r & 7) << 4); // XOR swizzle (16B slots)
      *(uint32_t*)(&xq[r * DK + byteoff]) = p;
    }
  }
  __syncthreads();

  // ---- 4 N-panels of 128 columns each; x LDS tile reused 4x ----
  for (int panel = 0; panel < 4; ++panel) {
    const int colBase = panel * NPANEL + wc * 64;

    int32x4 acc[4][4];
#pragma unroll
    for (int m = 0; m < 4; ++m)
#pragma unroll
      for (int n = 0; n < 4; ++n) acc[m][n] = 0;

#pragma unroll
    for (int ks = 0; ks < 8; ++ks) {
      const int kb = ks * 64 + lg * 16;
      int32x4 a[4], b[4];
#pragma unroll
      for (int m = 0; m < 4; ++m) {
        const int row = wr * 64 + m * 16 + lr;
        a[m] = *(const int32x4*)(&xq[row * DK + (kb ^ ((row & 7) << 4))]);
      }
#pragma unroll
      for (int n = 0; n < 4; ++n) {
        const int col = colBase + n * 16 + lr;
        b[n] = *(const int32x4*)(wq + (size_t)col * DK + kb);
      }
#pragma unroll
      for (int m = 0; m < 4; ++m)
#pragma unroll
        for (int n = 0; n < 4; ++n)
          acc[m][n] = __builtin_amdgcn_mfma_i32_16x16x64_i8(a[m], b[n], acc[m][n], 0, 0, 0);
    }

    // ---- epilogue: dequant (exact ref order: f32 divide) + bias ----
#pragma unroll
    for (int n = 0; n < 4; ++n) {
      const int col = colBase + n * 16 + lr;
      const float csv = cs[col];
      const float bv  = bias[col];
#pragma unroll
      for (int m = 0; m < 4; ++m) {
        const size_t rowg = mBase + (size_t)(wr * 64 + m * 16 + lg * 4);
        float* op = out + rowg * FN + col;
#pragma unroll
        for (int j = 0; j < 4; ++j) {
          op[(size_t)j * FN] = (float)acc[m][n][j] / csv + bv;
        }
      }
    }
  }
}

extern "C" void kernel_launch(void* const* d_in, const int* in_sizes, int n_in,
                              void* d_out, int out_size, void* d_ws, size_t ws_size,
                              hipStream_t stream) {
  const float* x    = (const float*)d_in[0];
  const float* kern = (const float*)d_in[1];
  const float* bias = (const float*)d_in[2];
  // d_in[3] = padding_mask: with fixed act bounds + eval mode it does not enter the math.

  int8_t* wq = (int8_t*)d_ws;                          // 256 KB
  float*  cs = (float*)((char*)d_ws + (size_t)FN * DK); // 2 KB

  wq_quant_kernel<<<4, 128, 0, stream>>>(kern, wq, cs);
  aqt_gemm_kernel<<<B_ROWS / BM, 256, 0, stream>>>(x, wq, cs, bias, (float*)d_out);
}

// Round 2
// 211.524 us; speedup vs baseline: 1.4579x; 1.4579x over previous
//
#include <hip/hip_runtime.h>
#include <stdint.h>

typedef int   int32x4  __attribute__((ext_vector_type(4)));
typedef float floatx4  __attribute__((ext_vector_type(4)));

#define B_ROWS 131072
#define DK 512           // K (= D)
#define FN 512           // N (= F)
#define BM 64            // rows per block (32 KB LDS -> 4 blocks/CU)
#define A_SCALE_F ((float)(127.0 / 6.0))

// ---------------- prepass: quantize weights into B-fragment layout -------------
// 32 blocks x 256 threads; block handles 16 columns, 16 row-groups of 32 rows.
// wq layout: [FN][DK] int8, k-contiguous -> MFMA B fragment = straight 16B load.
__global__ void wq_quant_kernel(const float* __restrict__ kern,  // [DK][FN]
                                int8_t* __restrict__ wq,         // [FN][DK]
                                float* __restrict__ cs) {        // [FN]
  __shared__ float smax[256];
  __shared__ float sscale[16];
  const int c = threadIdx.x & 15;        // col within block
  const int g = threadIdx.x >> 4;        // row-group 0..15 (32 rows each)
  const int col = blockIdx.x * 16 + c;

  float m = 0.f;
#pragma unroll 8
  for (int i = 0; i < 32; ++i) {
    m = fmaxf(m, fabsf(kern[(size_t)(g * 32 + i) * FN + col]));
  }
  smax[threadIdx.x] = m;
  __syncthreads();
  if (threadIdx.x < 16) {
    float mm = smax[threadIdx.x];
#pragma unroll
    for (int g2 = 1; g2 < 16; ++g2) mm = fmaxf(mm, smax[g2 * 16 + threadIdx.x]);
    const float wb = fmaxf(mm, 1e-6f);
    const float ws = 127.f / wb;               // f32 divide, matches jnp
    sscale[threadIdx.x] = ws;
    cs[blockIdx.x * 16 + threadIdx.x] = A_SCALE_F * ws;  // a_scale * w_scale
  }
  __syncthreads();
  const float ws = sscale[c];
  uint32_t* wq32 = (uint32_t*)(wq + (size_t)col * DK);
#pragma unroll
  for (int d4 = 0; d4 < 8; ++d4) {             // 32 rows -> 8 packed words
    uint32_t p = 0;
#pragma unroll
    for (int j = 0; j < 4; ++j) {
      float v = kern[(size_t)(g * 32 + d4 * 4 + j) * FN + col] * ws;
      v = floorf(v + 0.5f);                    // AQT round: floor(v+0.5)
      v = fminf(fmaxf(v, -127.f), 127.f);
      p |= ((uint32_t)((int)v & 255)) << (8 * j);
    }
    wq32[g * 8 + d4] = p;
  }
}

// ---------------- main GEMM ----------------------------------------------------
// 2048 blocks x 256 threads (4 waves; wave w owns cols [w*128, w*128+128)).
// LDS: 64x512 int8 x-tile, XOR-swizzled (16B slots) for the stride-512B b128 reads.
__global__ __launch_bounds__(256, 4)
void aqt_gemm_kernel(const float* __restrict__ x,     // [B_ROWS][DK]
                     const int8_t* __restrict__ wq,   // [FN][DK]
                     const float* __restrict__ cs,    // [FN]
                     const float* __restrict__ bias,  // [FN]
                     float* __restrict__ out) {       // [B_ROWS][FN]
  __shared__ __align__(16) char xq[BM * DK];          // 32 KB

  const int tid  = threadIdx.x;
  const int lane = tid & 63;
  const int wv   = tid >> 6;        // 0..3 -> column strip w*128
  const int lr   = lane & 15;       // fragment row/col
  const int lg   = lane >> 4;       // k-group (0..3)

  const size_t mBase = (size_t)blockIdx.x * BM;
  const float* xg = x + mBase * DK;

  // ---- stage: quantize x tile (fp32 -> int8) into swizzled LDS ----
  {
    const int c4 = tid & 127;       // float4 index within a row
    const int rg = tid >> 7;        // 0..1
#pragma unroll
    for (int it0 = 0; it0 < 32; it0 += 8) {
      floatx4 v[8];
#pragma unroll
      for (int u = 0; u < 8; ++u) {
        const int r = (it0 + u) * 2 + rg;
        v[u] = *(const floatx4*)(xg + (size_t)r * DK + c4 * 4);
      }
#pragma unroll
      for (int u = 0; u < 8; ++u) {
        const int r = (it0 + u) * 2 + rg;
        uint32_t p = 0;
#pragma unroll
        for (int j = 0; j < 4; ++j) {
          float q = floorf(v[u][j] * A_SCALE_F + 0.5f);   // AQT round
          q = fminf(fmaxf(q, -127.f), 127.f);
          p |= ((uint32_t)((int)q & 255)) << (8 * j);
        }
        *(uint32_t*)(&xq[r * DK + ((c4 * 4) ^ ((r & 7) << 4))]) = p;
      }
    }
  }
  __syncthreads();

  // ---- 2 panels of 64 cols per wave; x LDS tile shared by all 4 waves ----
  const int colW = wv * 128;
#pragma unroll
  for (int p = 0; p < 2; ++p) {
    const int colBase = colW + p * 64;

    int32x4 acc[4][4];
#pragma unroll
    for (int m = 0; m < 4; ++m)
#pragma unroll
      for (int n = 0; n < 4; ++n) acc[m][n] = 0;

#pragma unroll
    for (int ks = 0; ks < 8; ++ks) {
      const int kb = ks * 64 + lg * 16;
      int32x4 a[4], b[4];
#pragma unroll
      for (int m = 0; m < 4; ++m) {
        const int row = m * 16 + lr;
        a[m] = *(const int32x4*)(&xq[row * DK + (kb ^ ((row & 7) << 4))]);
      }
#pragma unroll
      for (int n = 0; n < 4; ++n) {
        const int col = colBase + n * 16 + lr;
        b[n] = *(const int32x4*)(wq + (size_t)col * DK + kb);
      }
#pragma unroll
      for (int m = 0; m < 4; ++m)
#pragma unroll
        for (int n = 0; n < 4; ++n)
          acc[m][n] = __builtin_amdgcn_mfma_i32_16x16x64_i8(a[m], b[n], acc[m][n], 0, 0, 0);
    }

    // ---- epilogue: dequant (exact ref order: f32 divide) + bias ----
#pragma unroll
    for (int n = 0; n < 4; ++n) {
      const int col = colBase + n * 16 + lr;
      const float csv = cs[col];
      const float bv  = bias[col];
#pragma unroll
      for (int m = 0; m < 4; ++m) {
        const size_t rowg = mBase + (size_t)(m * 16 + lg * 4);
        float* op = out + rowg * FN + col;
#pragma unroll
        for (int j = 0; j < 4; ++j) {
          op[(size_t)j * FN] = (float)acc[m][n][j] / csv + bv;
        }
      }
    }
  }
}

extern "C" void kernel_launch(void* const* d_in, const int* in_sizes, int n_in,
                              void* d_out, int out_size, void* d_ws, size_t ws_size,
                              hipStream_t stream) {
  const float* x    = (const float*)d_in[0];
  const float* kern = (const float*)d_in[1];
  const float* bias = (const float*)d_in[2];
  // d_in[3] = padding_mask: with fixed act bounds + eval mode it does not enter the math.

  int8_t* wq = (int8_t*)d_ws;                           // 256 KB
  float*  cs = (float*)((char*)d_ws + (size_t)FN * DK); // 2 KB

  wq_quant_kernel<<<32, 256, 0, stream>>>(kern, wq, cs);
  aqt_gemm_kernel<<<B_ROWS / BM, 256, 0, stream>>>(x, wq, cs, bias, (float*)d_out);
}